// Round 6
// baseline (344.180 us; speedup 1.0000x reference)
//
#include <hip/hip_runtime.h>
#include <hip/hip_bf16.h>

#define LN_EPS 1e-5f

typedef __attribute__((ext_vector_type(8))) short short8_t;
typedef __attribute__((ext_vector_type(4))) float float4_t;

__device__ __forceinline__ unsigned short f2bf(float x) {
    unsigned u = __builtin_bit_cast(unsigned, x);
    unsigned r = (u + 0x7FFFu + ((u >> 16) & 1u)) >> 16;
    return (unsigned short)r;
}

__device__ __forceinline__ float gelu_erf(float p) {
    return 0.5f * p * (1.0f + erff(p * 0.70710678118654752f));
}

// stage W^T (64 out-cols x 128 k) into swizzled LDS. 256 threads.
__device__ __forceinline__ void stage_w64(const float* __restrict__ W,
                                          unsigned short* Wbuf, int t) {
    const int c  = t & 63;
    const int kb = (t >> 6) * 32;
#pragma unroll
    for (int kk = 0; kk < 32; kk += 8) {
        unsigned short tmp[8];
#pragma unroll
        for (int i = 0; i < 8; ++i)
            tmp[i] = f2bf(W[(size_t)(kb + kk + i) * 64 + c]);
        unsigned idx = (unsigned)(c * 128 + kb + kk) ^ (unsigned)((c & 7) << 3);
        *(uint4*)&Wbuf[idx] = *(const uint4*)tmp;
    }
}

// ============ Kernel A: hv = LN(GELU(X @ W_node)) — barrier-free wave tiles ============
__global__ __launch_bounds__(256) void node_proj_kernel(
    const float* __restrict__ X, const float* __restrict__ W,
    const float* __restrict__ g, const float* __restrict__ b,
    float* __restrict__ out, int N)
{
    __shared__ __align__(16) unsigned short Wbuf[64 * 128];
    stage_w64(W, Wbuf, threadIdx.x);
    const int lane = threadIdx.x & 63;
    const int r16  = lane & 15;
    const int ks   = (lane >> 4) * 8;
    const int cq   = lane >> 4;
    float gv[4], bv[4];
#pragma unroll
    for (int ct = 0; ct < 4; ++ct) { gv[ct] = g[ct * 16 + r16]; bv[ct] = b[ct * 16 + r16]; }
    __syncthreads();

    const int gw = (int)((blockIdx.x * blockDim.x + threadIdx.x) >> 6);
    const int nw = (int)((gridDim.x * blockDim.x) >> 6);
    const int ntiles = (N + 15) >> 4;
    int tile = gw;
    if (tile >= ntiles) return;

    float4 pf[8];
    {
        const float* base = X + (size_t)min(tile * 16 + r16, N - 1) * 128;
#pragma unroll
        for (int kt = 0; kt < 4; ++kt) {
            pf[2 * kt]     = *(const float4*)(base + kt * 32 + ks);
            pf[2 * kt + 1] = *(const float4*)(base + kt * 32 + ks + 4);
        }
    }

    while (true) {
        const int r0 = tile * 16;
        short8_t a[4];
#pragma unroll
        for (int kt = 0; kt < 4; ++kt) {
            const float4 u = pf[2 * kt], v = pf[2 * kt + 1];
            short8_t t8;
            t8[0] = (short)f2bf(u.x); t8[1] = (short)f2bf(u.y);
            t8[2] = (short)f2bf(u.z); t8[3] = (short)f2bf(u.w);
            t8[4] = (short)f2bf(v.x); t8[5] = (short)f2bf(v.y);
            t8[6] = (short)f2bf(v.z); t8[7] = (short)f2bf(v.w);
            a[kt] = t8;
        }
        const int nt = tile + nw;
        if (nt < ntiles) {
            const float* base = X + (size_t)min(nt * 16 + r16, N - 1) * 128;
#pragma unroll
            for (int kt = 0; kt < 4; ++kt) {
                pf[2 * kt]     = *(const float4*)(base + kt * 32 + ks);
                pf[2 * kt + 1] = *(const float4*)(base + kt * 32 + ks + 4);
            }
        }

        float4_t acc[4];
#pragma unroll
        for (int ct = 0; ct < 4; ++ct) { acc[ct].x = 0.f; acc[ct].y = 0.f; acc[ct].z = 0.f; acc[ct].w = 0.f; }
#pragma unroll
        for (int ct = 0; ct < 4; ++ct) {
            const int c = ct * 16 + r16;
#pragma unroll
            for (int kt = 0; kt < 4; ++kt) {
                unsigned idx = (unsigned)(c * 128 + kt * 32 + ks) ^ (unsigned)((c & 7) << 3);
                short8_t bf = *(const short8_t*)&Wbuf[idx];
                acc[ct] = __builtin_amdgcn_mfma_f32_16x16x32_bf16(a[kt], bf, acc[ct], 0, 0, 0);
            }
        }

#pragma unroll
        for (int j = 0; j < 4; ++j) {
            float p0 = gelu_erf(acc[0][j]), p1 = gelu_erf(acc[1][j]);
            float p2 = gelu_erf(acc[2][j]), p3 = gelu_erf(acc[3][j]);
            float s = (p0 + p1) + (p2 + p3);
            s += __shfl_xor(s, 1); s += __shfl_xor(s, 2);
            s += __shfl_xor(s, 4); s += __shfl_xor(s, 8);
            const float mean = s * (1.0f / 64.0f);
            float d0 = p0 - mean, d1 = p1 - mean, d2 = p2 - mean, d3 = p3 - mean;
            float vs = d0 * d0 + d1 * d1 + d2 * d2 + d3 * d3;
            vs += __shfl_xor(vs, 1); vs += __shfl_xor(vs, 2);
            vs += __shfl_xor(vs, 4); vs += __shfl_xor(vs, 8);
            const float inv = rsqrtf(vs * (1.0f / 64.0f) + LN_EPS);
            const int r = r0 + cq * 4 + j;
            if (r < N) {
                float dd[4] = { d0, d1, d2, d3 };
#pragma unroll
                for (int ct = 0; ct < 4; ++ct)
                    out[(size_t)r * 64 + ct * 16 + r16] = dd[ct] * inv * gv[ct] + bv[ct];
            }
        }
        if (nt >= ntiles) break;
        tile = nt;
    }
}

// ============ K1: he = exp(LN(EF @ W_edge)) — pure streaming GEMM, no graph traffic ============
__global__ __launch_bounds__(256) void he_gemm_kernel(
    const float* __restrict__ EF, const float* __restrict__ W,
    const float* __restrict__ g, const float* __restrict__ b,
    float* __restrict__ heb, int E)
{
    __shared__ __align__(16) unsigned short Wbuf[64 * 128];
    stage_w64(W, Wbuf, threadIdx.x);
    const int lane = threadIdx.x & 63;
    const int r16  = lane & 15;
    const int ks   = (lane >> 4) * 8;
    const int cq   = lane >> 4;
    float gv[4], bv[4];
#pragma unroll
    for (int ct = 0; ct < 4; ++ct) { gv[ct] = g[ct * 16 + r16]; bv[ct] = b[ct * 16 + r16]; }
    __syncthreads();

    const int gw = (int)((blockIdx.x * blockDim.x + threadIdx.x) >> 6);
    const int nw = (int)((gridDim.x * blockDim.x) >> 6);
    const int ntiles = (E + 15) >> 4;
    int tile = gw;
    if (tile >= ntiles) return;

    float4 pf[8];
    {
        const float* base = EF + (size_t)min(tile * 16 + r16, E - 1) * 128;
#pragma unroll
        for (int kt = 0; kt < 4; ++kt) {
            pf[2 * kt]     = *(const float4*)(base + kt * 32 + ks);
            pf[2 * kt + 1] = *(const float4*)(base + kt * 32 + ks + 4);
        }
    }

    while (true) {
        const int e0 = tile * 16;
        short8_t a[4];
#pragma unroll
        for (int kt = 0; kt < 4; ++kt) {
            const float4 u = pf[2 * kt], v = pf[2 * kt + 1];
            short8_t t8;
            t8[0] = (short)f2bf(u.x); t8[1] = (short)f2bf(u.y);
            t8[2] = (short)f2bf(u.z); t8[3] = (short)f2bf(u.w);
            t8[4] = (short)f2bf(v.x); t8[5] = (short)f2bf(v.y);
            t8[6] = (short)f2bf(v.z); t8[7] = (short)f2bf(v.w);
            a[kt] = t8;
        }
        const int nt = tile + nw;
        if (nt < ntiles) {
            const float* base = EF + (size_t)min(nt * 16 + r16, E - 1) * 128;
#pragma unroll
            for (int kt = 0; kt < 4; ++kt) {
                pf[2 * kt]     = *(const float4*)(base + kt * 32 + ks);
                pf[2 * kt + 1] = *(const float4*)(base + kt * 32 + ks + 4);
            }
        }

        float4_t acc[4];
#pragma unroll
        for (int ct = 0; ct < 4; ++ct) { acc[ct].x = 0.f; acc[ct].y = 0.f; acc[ct].z = 0.f; acc[ct].w = 0.f; }
#pragma unroll
        for (int ct = 0; ct < 4; ++ct) {
            const int c = ct * 16 + r16;
#pragma unroll
            for (int kt = 0; kt < 4; ++kt) {
                unsigned idx = (unsigned)(c * 128 + kt * 32 + ks) ^ (unsigned)((c & 7) << 3);
                short8_t bf = *(const short8_t*)&Wbuf[idx];
                acc[ct] = __builtin_amdgcn_mfma_f32_16x16x32_bf16(a[kt], bf, acc[ct], 0, 0, 0);
            }
        }

#pragma unroll
        for (int j = 0; j < 4; ++j) {
            float s = acc[0][j] + acc[1][j] + acc[2][j] + acc[3][j];
            s += __shfl_xor(s, 1); s += __shfl_xor(s, 2);
            s += __shfl_xor(s, 4); s += __shfl_xor(s, 8);
            const float mean = s * (1.0f / 64.0f);
            float d0 = acc[0][j] - mean, d1 = acc[1][j] - mean;
            float d2 = acc[2][j] - mean, d3 = acc[3][j] - mean;
            float vs = d0 * d0 + d1 * d1 + d2 * d2 + d3 * d3;
            vs += __shfl_xor(vs, 1); vs += __shfl_xor(vs, 2);
            vs += __shfl_xor(vs, 4); vs += __shfl_xor(vs, 8);
            const float inv = rsqrtf(vs * (1.0f / 64.0f) + LN_EPS);
            const int e = e0 + cq * 4 + j;
            if (e < E) {
                float dd[4] = { d0, d1, d2, d3 };
#pragma unroll
                for (int ct = 0; ct < 4; ++ct)
                    heb[(size_t)e * 64 + ct * 16 + r16] = __expf(dd[ct] * inv * gv[ct] + bv[ct]);
            }
        }
        if (nt >= ntiles) break;
        tile = nt;
    }
}

// ============ K2: h[dst] += hv[src] * he — one wave per edge, row-coalesced ============
__global__ __launch_bounds__(256) void edge_scatter_kernel(
    const float* __restrict__ heb,
    const int* __restrict__ src, const int* __restrict__ dst,
    const float* __restrict__ hv, float* __restrict__ h, int E)
{
    const int lane = threadIdx.x & 63;
    const int gw = (int)((blockIdx.x * blockDim.x + threadIdx.x) >> 6);
    const int nw = (int)((gridDim.x * blockDim.x) >> 6);
    const int ngroups = (E + 7) >> 3;
    int gidx = gw;
    if (gidx >= ngroups) return;

    int ps[8], pd[8];
#pragma unroll
    for (int u = 0; u < 8; ++u) {
        const int e = min(gidx * 8 + u, E - 1);
        ps[u] = src[e]; pd[u] = dst[e];
    }

    while (true) {
        const int e0 = gidx * 8;
        const int gn = gidx + nw;

        // issue all data loads for this group (8 he rows + 8 hv rows, coalesced 256B each)
        float hev[8], hvv[8];
#pragma unroll
        for (int u = 0; u < 8; ++u) {
            const int e = min(e0 + u, E - 1);
            hev[u] = heb[(size_t)e * 64 + lane];
            hvv[u] = hv[(size_t)ps[u] * 64 + lane];
        }

        // prefetch next group's src/dst (breaks the index->gather serial chain)
        int ns[8], nd[8];
        if (gn < ngroups) {
            const int en0 = gn * 8;
#pragma unroll
            for (int u = 0; u < 8; ++u) {
                const int e = min(en0 + u, E - 1);
                ns[u] = src[e]; nd[u] = dst[e];
            }
        }

        // multiply + one row-atomic per edge (256B contiguous)
#pragma unroll
        for (int u = 0; u < 8; ++u) {
            if (e0 + u < E)
                atomicAdd(h + (size_t)pd[u] * 64 + lane, hev[u] * hvv[u]);
        }

        if (gn >= ngroups) break;
        gidx = gn;
#pragma unroll
        for (int u = 0; u < 8; ++u) { ps[u] = ns[u]; pd[u] = nd[u]; }
    }
}

// ============ Kernel C: out = LN(GELU(H @ W_out)) — K=64, 128 cols ============
__global__ __launch_bounds__(256) void out_proj_kernel(
    const float* __restrict__ Hin, const float* __restrict__ W,
    const float* __restrict__ g, const float* __restrict__ b,
    float* __restrict__ out, int N)
{
    __shared__ __align__(16) unsigned short Wbuf[128 * 64];
    {
        const int t  = threadIdx.x;
        const int c  = t & 127;
        const int k0 = (t >> 7) * 32;
#pragma unroll
        for (int kk = 0; kk < 32; kk += 8) {
            unsigned short tmp[8];
#pragma unroll
            for (int i = 0; i < 8; ++i)
                tmp[i] = f2bf(W[(size_t)(k0 + kk + i) * 128 + c]);
            unsigned idx = (unsigned)(c * 64 + k0 + kk) ^ (unsigned)((c & 7) << 3);
            *(uint4*)&Wbuf[idx] = *(const uint4*)tmp;
        }
    }
    const int lane = threadIdx.x & 63;
    const int r16  = lane & 15;
    const int ks   = (lane >> 4) * 8;
    const int cq   = lane >> 4;
    float gv[8], bv[8];
#pragma unroll
    for (int ct = 0; ct < 8; ++ct) { gv[ct] = g[ct * 16 + r16]; bv[ct] = b[ct * 16 + r16]; }
    __syncthreads();

    const int gw = (int)((blockIdx.x * blockDim.x + threadIdx.x) >> 6);
    const int nw = (int)((gridDim.x * blockDim.x) >> 6);
    const int ntiles = (N + 15) >> 4;
    int tile = gw;
    if (tile >= ntiles) return;

    float4 pf[4];
    {
        const float* base = Hin + (size_t)min(tile * 16 + r16, N - 1) * 64;
#pragma unroll
        for (int kt = 0; kt < 2; ++kt) {
            pf[2 * kt]     = *(const float4*)(base + kt * 32 + ks);
            pf[2 * kt + 1] = *(const float4*)(base + kt * 32 + ks + 4);
        }
    }

    while (true) {
        const int r0 = tile * 16;
        short8_t a[2];
#pragma unroll
        for (int kt = 0; kt < 2; ++kt) {
            const float4 u = pf[2 * kt], v = pf[2 * kt + 1];
            short8_t t8;
            t8[0] = (short)f2bf(u.x); t8[1] = (short)f2bf(u.y);
            t8[2] = (short)f2bf(u.z); t8[3] = (short)f2bf(u.w);
            t8[4] = (short)f2bf(v.x); t8[5] = (short)f2bf(v.y);
            t8[6] = (short)f2bf(v.z); t8[7] = (short)f2bf(v.w);
            a[kt] = t8;
        }
        const int nt = tile + nw;
        if (nt < ntiles) {
            const float* base = Hin + (size_t)min(nt * 16 + r16, N - 1) * 64;
#pragma unroll
            for (int kt = 0; kt < 2; ++kt) {
                pf[2 * kt]     = *(const float4*)(base + kt * 32 + ks);
                pf[2 * kt + 1] = *(const float4*)(base + kt * 32 + ks + 4);
            }
        }

        float4_t acc[8];
#pragma unroll
        for (int ct = 0; ct < 8; ++ct) { acc[ct].x = 0.f; acc[ct].y = 0.f; acc[ct].z = 0.f; acc[ct].w = 0.f; }
#pragma unroll
        for (int ct = 0; ct < 8; ++ct) {
            const int c = ct * 16 + r16;
#pragma unroll
            for (int kt = 0; kt < 2; ++kt) {
                unsigned idx = (unsigned)(c * 64 + kt * 32 + ks) ^ (unsigned)((c & 7) << 3);
                short8_t bf = *(const short8_t*)&Wbuf[idx];
                acc[ct] = __builtin_amdgcn_mfma_f32_16x16x32_bf16(a[kt], bf, acc[ct], 0, 0, 0);
            }
        }

#pragma unroll
        for (int j = 0; j < 4; ++j) {
            float p[8];
            float s = 0.f;
#pragma unroll
            for (int ct = 0; ct < 8; ++ct) { p[ct] = gelu_erf(acc[ct][j]); s += p[ct]; }
            s += __shfl_xor(s, 1); s += __shfl_xor(s, 2);
            s += __shfl_xor(s, 4); s += __shfl_xor(s, 8);
            const float mean = s * (1.0f / 128.0f);
            float vs = 0.f;
#pragma unroll
            for (int ct = 0; ct < 8; ++ct) { p[ct] -= mean; vs += p[ct] * p[ct]; }
            vs += __shfl_xor(vs, 1); vs += __shfl_xor(vs, 2);
            vs += __shfl_xor(vs, 4); vs += __shfl_xor(vs, 8);
            const float inv = rsqrtf(vs * (1.0f / 128.0f) + LN_EPS);
            const int r = r0 + cq * 4 + j;
            if (r < N) {
#pragma unroll
                for (int ct = 0; ct < 8; ++ct)
                    out[(size_t)r * 128 + ct * 16 + r16] = p[ct] * inv * gv[ct] + bv[ct];
            }
        }
        if (nt >= ntiles) break;
        tile = nt;
    }
}

extern "C" void kernel_launch(void* const* d_in, const int* in_sizes, int n_in,
                              void* d_out, int out_size, void* d_ws, size_t ws_size,
                              hipStream_t stream) {
    const float* node_feats = (const float*)d_in[0];
    const float* edge_feats = (const float*)d_in[1];
    const int*   src        = (const int*)d_in[2];
    const int*   dst        = (const int*)d_in[3];
    const float* W_node     = (const float*)d_in[4];
    const float* ln_ng      = (const float*)d_in[5];
    const float* ln_nb      = (const float*)d_in[6];
    const float* W_edge     = (const float*)d_in[7];
    const float* ln_eg      = (const float*)d_in[8];
    const float* ln_eb      = (const float*)d_in[9];
    const float* W_out      = (const float*)d_in[10];
    const float* ln_og      = (const float*)d_in[11];
    const float* ln_ob      = (const float*)d_in[12];
    float* out = (float*)d_out;

    const int N = in_sizes[0] / 128;
    const int E = in_sizes[2];

    float* hv  = (float*)d_ws;                 // N*64 f32
    float* h   = hv + (size_t)N * 64;          // N*64 f32
    float* heb = h + (size_t)N * 64;           // E*64 f32 (200 MB)

    hipMemsetAsync(h, 0, (size_t)N * 64 * sizeof(float), stream);
    node_proj_kernel<<<784, 256, 0, stream>>>(node_feats, W_node, ln_ng, ln_nb, hv, N);
    he_gemm_kernel<<<1024, 256, 0, stream>>>(edge_feats, W_edge, ln_eg, ln_eb, heb, E);
    edge_scatter_kernel<<<2048, 256, 0, stream>>>(heb, src, dst, hv, h, E);
    out_proj_kernel<<<784, 256, 0, stream>>>(h, W_out, ln_og, ln_ob, out, N);
}

// Round 7
// 228.139 us; speedup vs baseline: 1.5086x; 1.5086x over previous
//
#include <hip/hip_runtime.h>
#include <hip/hip_bf16.h>

#define LN_EPS 1e-5f

typedef __attribute__((ext_vector_type(8))) short short8_t;
typedef __attribute__((ext_vector_type(2))) short short2v;
typedef __attribute__((ext_vector_type(4))) float float4_t;

__device__ __forceinline__ unsigned short f2bf(float x) {
    unsigned u = __builtin_bit_cast(unsigned, x);
    unsigned r = (u + 0x7FFFu + ((u >> 16) & 1u)) >> 16;
    return (unsigned short)r;
}

__device__ __forceinline__ float bf2f(unsigned short x) {
    return __builtin_bit_cast(float, (unsigned)x << 16);
}

__device__ __forceinline__ float gelu_erf(float p) {
    return 0.5f * p * (1.0f + erff(p * 0.70710678118654752f));
}

// packed bf16 atomic add: adds (lo,hi) to the two bf16 at *addr (4B-aligned)
__device__ __forceinline__ void atomic_pk_add_bf16(unsigned* addr, float lo, float hi) {
#if __has_builtin(__builtin_amdgcn_global_atomic_fadd_v2bf16)
    short2v v;
    v[0] = (short)f2bf(lo);
    v[1] = (short)f2bf(hi);
    __builtin_amdgcn_global_atomic_fadd_v2bf16(
        (__attribute__((address_space(1))) short2v*)(unsigned long long)addr, v);
#else
    unsigned old = __hip_atomic_load(addr, __ATOMIC_RELAXED, __HIP_MEMORY_SCOPE_AGENT);
    unsigned assumed;
    do {
        assumed = old;
        float a0 = bf2f((unsigned short)(assumed & 0xFFFFu)) + lo;
        float a1 = bf2f((unsigned short)(assumed >> 16)) + hi;
        unsigned pk = (unsigned)f2bf(a0) | ((unsigned)f2bf(a1) << 16);
        old = atomicCAS(addr, assumed, pk);
    } while (old != assumed);
#endif
}

// stage W^T (64 out-cols x 128 k) into swizzled LDS. 256 threads.
__device__ __forceinline__ void stage_w64(const float* __restrict__ W,
                                          unsigned short* Wbuf, int t) {
    const int c  = t & 63;
    const int kb = (t >> 6) * 32;
#pragma unroll
    for (int kk = 0; kk < 32; kk += 8) {
        unsigned short tmp[8];
#pragma unroll
        for (int i = 0; i < 8; ++i)
            tmp[i] = f2bf(W[(size_t)(kb + kk + i) * 64 + c]);
        unsigned idx = (unsigned)(c * 128 + kb + kk) ^ (unsigned)((c & 7) << 3);
        *(uint4*)&Wbuf[idx] = *(const uint4*)tmp;
    }
}

// ============ Kernel A: hv = LN(GELU(X @ W_node)) -> bf16 ============
__global__ __launch_bounds__(256) void node_proj_kernel(
    const float* __restrict__ X, const float* __restrict__ W,
    const float* __restrict__ g, const float* __restrict__ b,
    unsigned short* __restrict__ outb, int N)
{
    __shared__ __align__(16) unsigned short Wbuf[64 * 128];
    stage_w64(W, Wbuf, threadIdx.x);
    const int lane = threadIdx.x & 63;
    const int r16  = lane & 15;
    const int ks   = (lane >> 4) * 8;
    const int cq   = lane >> 4;
    float gv[4], bv[4];
#pragma unroll
    for (int ct = 0; ct < 4; ++ct) { gv[ct] = g[ct * 16 + r16]; bv[ct] = b[ct * 16 + r16]; }
    __syncthreads();

    const int gw = (int)((blockIdx.x * blockDim.x + threadIdx.x) >> 6);
    const int nw = (int)((gridDim.x * blockDim.x) >> 6);
    const int ntiles = (N + 15) >> 4;
    int tile = gw;
    if (tile >= ntiles) return;

    float4 pf[8];
    {
        const float* base = X + (size_t)min(tile * 16 + r16, N - 1) * 128;
#pragma unroll
        for (int kt = 0; kt < 4; ++kt) {
            pf[2 * kt]     = *(const float4*)(base + kt * 32 + ks);
            pf[2 * kt + 1] = *(const float4*)(base + kt * 32 + ks + 4);
        }
    }

    while (true) {
        const int r0 = tile * 16;
        short8_t a[4];
#pragma unroll
        for (int kt = 0; kt < 4; ++kt) {
            const float4 u = pf[2 * kt], v = pf[2 * kt + 1];
            short8_t t8;
            t8[0] = (short)f2bf(u.x); t8[1] = (short)f2bf(u.y);
            t8[2] = (short)f2bf(u.z); t8[3] = (short)f2bf(u.w);
            t8[4] = (short)f2bf(v.x); t8[5] = (short)f2bf(v.y);
            t8[6] = (short)f2bf(v.z); t8[7] = (short)f2bf(v.w);
            a[kt] = t8;
        }
        const int nt = tile + nw;
        if (nt < ntiles) {
            const float* base = X + (size_t)min(nt * 16 + r16, N - 1) * 128;
#pragma unroll
            for (int kt = 0; kt < 4; ++kt) {
                pf[2 * kt]     = *(const float4*)(base + kt * 32 + ks);
                pf[2 * kt + 1] = *(const float4*)(base + kt * 32 + ks + 4);
            }
        }

        float4_t acc[4];
#pragma unroll
        for (int ct = 0; ct < 4; ++ct) { acc[ct].x = 0.f; acc[ct].y = 0.f; acc[ct].z = 0.f; acc[ct].w = 0.f; }
#pragma unroll
        for (int ct = 0; ct < 4; ++ct) {
            const int c = ct * 16 + r16;
#pragma unroll
            for (int kt = 0; kt < 4; ++kt) {
                unsigned idx = (unsigned)(c * 128 + kt * 32 + ks) ^ (unsigned)((c & 7) << 3);
                short8_t bf = *(const short8_t*)&Wbuf[idx];
                acc[ct] = __builtin_amdgcn_mfma_f32_16x16x32_bf16(a[kt], bf, acc[ct], 0, 0, 0);
            }
        }

#pragma unroll
        for (int j = 0; j < 4; ++j) {
            float p0 = gelu_erf(acc[0][j]), p1 = gelu_erf(acc[1][j]);
            float p2 = gelu_erf(acc[2][j]), p3 = gelu_erf(acc[3][j]);
            float s = (p0 + p1) + (p2 + p3);
            s += __shfl_xor(s, 1); s += __shfl_xor(s, 2);
            s += __shfl_xor(s, 4); s += __shfl_xor(s, 8);
            const float mean = s * (1.0f / 64.0f);
            float d0 = p0 - mean, d1 = p1 - mean, d2 = p2 - mean, d3 = p3 - mean;
            float vs = d0 * d0 + d1 * d1 + d2 * d2 + d3 * d3;
            vs += __shfl_xor(vs, 1); vs += __shfl_xor(vs, 2);
            vs += __shfl_xor(vs, 4); vs += __shfl_xor(vs, 8);
            const float inv = rsqrtf(vs * (1.0f / 64.0f) + LN_EPS);
            const int r = r0 + cq * 4 + j;
            if (r < N) {
                float dd[4] = { d0, d1, d2, d3 };
#pragma unroll
                for (int ct = 0; ct < 4; ++ct)
                    outb[(size_t)r * 64 + ct * 16 + r16] = f2bf(dd[ct] * inv * gv[ct] + bv[ct]);
            }
        }
        if (nt >= ntiles) break;
        tile = nt;
    }
}

// ============ Kernel B: edge — barrier-free, bf16 hv gather, pk-bf16 atomics ============
__global__ __launch_bounds__(256) void edge_kernel(
    const float* __restrict__ EF, const float* __restrict__ W,
    const float* __restrict__ g, const float* __restrict__ b,
    const int* __restrict__ src, const int* __restrict__ dst,
    const unsigned short* __restrict__ hvb, unsigned* __restrict__ hb, int E)
{
    __shared__ __align__(16) unsigned short Wbuf[64 * 128];
    stage_w64(W, Wbuf, threadIdx.x);
    const int lane = threadIdx.x & 63;
    const int r16  = lane & 15;
    const int ks   = (lane >> 4) * 8;
    const int cq   = lane >> 4;
    float gv[4], bv[4];
#pragma unroll
    for (int ct = 0; ct < 4; ++ct) { gv[ct] = g[ct * 16 + r16]; bv[ct] = b[ct * 16 + r16]; }
    __syncthreads();

    const int gw = (int)((blockIdx.x * blockDim.x + threadIdx.x) >> 6);
    const int nw = (int)((gridDim.x * blockDim.x) >> 6);
    const int ntiles = (E + 15) >> 4;
    int tile = gw;
    if (tile >= ntiles) return;

    float4 pf[8];
    int psv[4], pdv[4];
    {
        const float* base = EF + (size_t)min(tile * 16 + r16, E - 1) * 128;
#pragma unroll
        for (int kt = 0; kt < 4; ++kt) {
            pf[2 * kt]     = *(const float4*)(base + kt * 32 + ks);
            pf[2 * kt + 1] = *(const float4*)(base + kt * 32 + ks + 4);
        }
#pragma unroll
        for (int j = 0; j < 4; ++j) {
            const int e = min(tile * 16 + cq * 4 + j, E - 1);
            psv[j] = src[e]; pdv[j] = dst[e];
        }
    }

    while (true) {
        const int e0 = tile * 16;
        int sv[4], dv[4];
#pragma unroll
        for (int j = 0; j < 4; ++j) { sv[j] = psv[j]; dv[j] = pdv[j]; }

        // early hv gather (bf16, 128B rows) — in flight across convert+MFMA+LN
        float hvv[4][4];
#pragma unroll
        for (int j = 0; j < 4; ++j)
#pragma unroll
            for (int ct = 0; ct < 4; ++ct)
                hvv[j][ct] = bf2f(hvb[(size_t)sv[j] * 64 + ct * 16 + r16]);

        short8_t a[4];
#pragma unroll
        for (int kt = 0; kt < 4; ++kt) {
            const float4 u = pf[2 * kt], v = pf[2 * kt + 1];
            short8_t t8;
            t8[0] = (short)f2bf(u.x); t8[1] = (short)f2bf(u.y);
            t8[2] = (short)f2bf(u.z); t8[3] = (short)f2bf(u.w);
            t8[4] = (short)f2bf(v.x); t8[5] = (short)f2bf(v.y);
            t8[6] = (short)f2bf(v.z); t8[7] = (short)f2bf(v.w);
            a[kt] = t8;
        }

        // prefetch next tile (A rows + src/dst)
        const int nt = tile + nw;
        if (nt < ntiles) {
            const float* base = EF + (size_t)min(nt * 16 + r16, E - 1) * 128;
#pragma unroll
            for (int kt = 0; kt < 4; ++kt) {
                pf[2 * kt]     = *(const float4*)(base + kt * 32 + ks);
                pf[2 * kt + 1] = *(const float4*)(base + kt * 32 + ks + 4);
            }
#pragma unroll
            for (int j = 0; j < 4; ++j) {
                const int e = min(nt * 16 + cq * 4 + j, E - 1);
                psv[j] = src[e]; pdv[j] = dst[e];
            }
        }

        float4_t acc[4];
#pragma unroll
        for (int ct = 0; ct < 4; ++ct) { acc[ct].x = 0.f; acc[ct].y = 0.f; acc[ct].z = 0.f; acc[ct].w = 0.f; }
#pragma unroll
        for (int ct = 0; ct < 4; ++ct) {
            const int c = ct * 16 + r16;
#pragma unroll
            for (int kt = 0; kt < 4; ++kt) {
                unsigned idx = (unsigned)(c * 128 + kt * 32 + ks) ^ (unsigned)((c & 7) << 3);
                short8_t bf = *(const short8_t*)&Wbuf[idx];
                acc[ct] = __builtin_amdgcn_mfma_f32_16x16x32_bf16(a[kt], bf, acc[ct], 0, 0, 0);
            }
        }

#pragma unroll
        for (int j = 0; j < 4; ++j) {
            float s = acc[0][j] + acc[1][j] + acc[2][j] + acc[3][j];
            s += __shfl_xor(s, 1); s += __shfl_xor(s, 2);
            s += __shfl_xor(s, 4); s += __shfl_xor(s, 8);
            const float mean = s * (1.0f / 64.0f);
            float d0 = acc[0][j] - mean, d1 = acc[1][j] - mean;
            float d2 = acc[2][j] - mean, d3 = acc[3][j] - mean;
            float vs = d0 * d0 + d1 * d1 + d2 * d2 + d3 * d3;
            vs += __shfl_xor(vs, 1); vs += __shfl_xor(vs, 2);
            vs += __shfl_xor(vs, 4); vs += __shfl_xor(vs, 8);
            const float inv = rsqrtf(vs * (1.0f / 64.0f) + LN_EPS);
            const int e = e0 + cq * 4 + j;
            float dd[4] = { d0, d1, d2, d3 };
#pragma unroll
            for (int ct = 0; ct < 4; ++ct) {
                const float he  = __expf(dd[ct] * inv * gv[ct] + bv[ct]);
                const float val = he * hvv[j][ct];
                const float hi  = __shfl_xor(val, 1);   // partner col's value
                if (e < E && !(lane & 1)) {
                    // lane owns cols (c, c+1), c = ct*16 + r16 (even) -> one dword
                    unsigned* addr = hb + (size_t)dv[j] * 32 + ct * 8 + (r16 >> 1);
                    atomic_pk_add_bf16(addr, val, hi);
                }
            }
        }
        if (nt >= ntiles) break;
        tile = nt;
    }
}

// ============ Kernel C: out = LN(GELU(H @ W_out)) — bf16 H input, K=64, 128 cols ============
__global__ __launch_bounds__(256) void out_proj_kernel(
    const unsigned short* __restrict__ Hb, const float* __restrict__ W,
    const float* __restrict__ g, const float* __restrict__ b,
    float* __restrict__ out, int N)
{
    __shared__ __align__(16) unsigned short Wbuf[128 * 64];
    {
        const int t  = threadIdx.x;
        const int c  = t & 127;
        const int k0 = (t >> 7) * 32;
#pragma unroll
        for (int kk = 0; kk < 32; kk += 8) {
            unsigned short tmp[8];
#pragma unroll
            for (int i = 0; i < 8; ++i)
                tmp[i] = f2bf(W[(size_t)(k0 + kk + i) * 128 + c]);
            unsigned idx = (unsigned)(c * 64 + k0 + kk) ^ (unsigned)((c & 7) << 3);
            *(uint4*)&Wbuf[idx] = *(const uint4*)tmp;
        }
    }
    const int lane = threadIdx.x & 63;
    const int r16  = lane & 15;
    const int ks   = (lane >> 4) * 8;
    const int cq   = lane >> 4;
    float gv[8], bv[8];
#pragma unroll
    for (int ct = 0; ct < 8; ++ct) { gv[ct] = g[ct * 16 + r16]; bv[ct] = b[ct * 16 + r16]; }
    __syncthreads();

    const int gw = (int)((blockIdx.x * blockDim.x + threadIdx.x) >> 6);
    const int nw = (int)((gridDim.x * blockDim.x) >> 6);
    const int ntiles = (N + 15) >> 4;
    int tile = gw;
    if (tile >= ntiles) return;

    short8_t pa[2];
    {
        const unsigned short* base = Hb + (size_t)min(tile * 16 + r16, N - 1) * 64;
        pa[0] = *(const short8_t*)(base + ks);
        pa[1] = *(const short8_t*)(base + 32 + ks);
    }

    while (true) {
        const int r0 = tile * 16;
        short8_t a[2];
        a[0] = pa[0]; a[1] = pa[1];

        const int nt = tile + nw;
        if (nt < ntiles) {
            const unsigned short* base = Hb + (size_t)min(nt * 16 + r16, N - 1) * 64;
            pa[0] = *(const short8_t*)(base + ks);
            pa[1] = *(const short8_t*)(base + 32 + ks);
        }

        float4_t acc[8];
#pragma unroll
        for (int ct = 0; ct < 8; ++ct) { acc[ct].x = 0.f; acc[ct].y = 0.f; acc[ct].z = 0.f; acc[ct].w = 0.f; }
#pragma unroll
        for (int ct = 0; ct < 8; ++ct) {
            const int c = ct * 16 + r16;
#pragma unroll
            for (int kt = 0; kt < 2; ++kt) {
                unsigned idx = (unsigned)(c * 64 + kt * 32 + ks) ^ (unsigned)((c & 7) << 3);
                short8_t bf = *(const short8_t*)&Wbuf[idx];
                acc[ct] = __builtin_amdgcn_mfma_f32_16x16x32_bf16(a[kt], bf, acc[ct], 0, 0, 0);
            }
        }

#pragma unroll
        for (int j = 0; j < 4; ++j) {
            float p[8];
            float s = 0.f;
#pragma unroll
            for (int ct = 0; ct < 8; ++ct) { p[ct] = gelu_erf(acc[ct][j]); s += p[ct]; }
            s += __shfl_xor(s, 1); s += __shfl_xor(s, 2);
            s += __shfl_xor(s, 4); s += __shfl_xor(s, 8);
            const float mean = s * (1.0f / 128.0f);
            float vs = 0.f;
#pragma unroll
            for (int ct = 0; ct < 8; ++ct) { p[ct] -= mean; vs += p[ct] * p[ct]; }
            vs += __shfl_xor(vs, 1); vs += __shfl_xor(vs, 2);
            vs += __shfl_xor(vs, 4); vs += __shfl_xor(vs, 8);
            const float inv = rsqrtf(vs * (1.0f / 128.0f) + LN_EPS);
            const int r = r0 + cq * 4 + j;
            if (r < N) {
#pragma unroll
                for (int ct = 0; ct < 8; ++ct)
                    out[(size_t)r * 128 + ct * 16 + r16] = p[ct] * inv * gv[ct] + bv[ct];
            }
        }
        if (nt >= ntiles) break;
        tile = nt;
    }
}

extern "C" void kernel_launch(void* const* d_in, const int* in_sizes, int n_in,
                              void* d_out, int out_size, void* d_ws, size_t ws_size,
                              hipStream_t stream) {
    const float* node_feats = (const float*)d_in[0];
    const float* edge_feats = (const float*)d_in[1];
    const int*   src        = (const int*)d_in[2];
    const int*   dst        = (const int*)d_in[3];
    const float* W_node     = (const float*)d_in[4];
    const float* ln_ng      = (const float*)d_in[5];
    const float* ln_nb      = (const float*)d_in[6];
    const float* W_edge     = (const float*)d_in[7];
    const float* ln_eg      = (const float*)d_in[8];
    const float* ln_eb      = (const float*)d_in[9];
    const float* W_out      = (const float*)d_in[10];
    const float* ln_og      = (const float*)d_in[11];
    const float* ln_ob      = (const float*)d_in[12];
    float* out = (float*)d_out;

    const int N = in_sizes[0] / 128;
    const int E = in_sizes[2];

    unsigned short* hvb = (unsigned short*)d_ws;        // N*64 bf16 (6.4 MB)
    unsigned short* hb  = hvb + (size_t)N * 64;         // N*64 bf16 (6.4 MB)

    hipMemsetAsync(hb, 0, (size_t)N * 64 * sizeof(unsigned short), stream);
    node_proj_kernel<<<784, 256, 0, stream>>>(node_feats, W_node, ln_ng, ln_nb, hvb, N);
    edge_kernel<<<1024, 256, 0, stream>>>(edge_feats, W_edge, ln_eg, ln_eb,
                                          src, dst, hvb, (unsigned*)hb, E);
    out_proj_kernel<<<784, 256, 0, stream>>>(hb, W_out, ln_og, ln_ob, out, N);
}